// Round 18
// baseline (176.937 us; speedup 1.0000x reference)
//
#include <hip/hip_runtime.h>
#include <hip/hip_bf16.h>
#include <math.h>

// NeighbourLoss: n=8192 pts, d=512, n_classes=1024 (8/class -> 7 positives/row).
// Outputs: loss, prec, pos_d, neg_d (4 floats).
// Pipeline: prep (sq + f16 convert) -> class-bucket build -> PER-CLASS exact
// fp32 positive pass (members cached in LDS once: 7x less read traffic than
// wave-per-point) -> symmetric f16 MFMA Gram sweep, 128x128 triangular tiles,
// 512 threads / 8 waves (64x32 per wave, acc=32 f32/lane -> 6 waves/SIMD),
// single 16KB LDS buffer, serial stage-then-compute (R17: 105us main) ->
// finalize.  Assumes n % 128 == 0, d % 32 == 0, n <= 8192.

#define MARGIN_F 0.1f

typedef unsigned short ushort_t;
typedef __attribute__((ext_vector_type(8))) _Float16 f16x8;
typedef __attribute__((ext_vector_type(4))) float f32x4;

// ---------------- prep: row squared norms + f16 convert ----------------
__global__ void nl_prep_kernel(const float* __restrict__ x, float* __restrict__ sq,
                               ushort_t* __restrict__ xh,
                               float* __restrict__ neg_total, unsigned int* __restrict__ neg_cnt,
                               int n, int d) {
  int row = blockIdx.x * blockDim.y + threadIdx.y;   // blockDim = (64,4)
  if (row >= n) return;
  const float* xr = x + (size_t)row * d;
  float s = 0.f;
  for (int k = threadIdx.x * 4; k < d; k += 64 * 4) {
    float4 v = *reinterpret_cast<const float4*>(xr + k);
    s = fmaf(v.x, v.x, s); s = fmaf(v.y, v.y, s);
    s = fmaf(v.z, v.z, s); s = fmaf(v.w, v.w, s);
    if (xh != nullptr) {
      float f[4] = {v.x, v.y, v.z, v.w};
      union { ushort_t u[4]; uint2 v2; } H;
#pragma unroll
      for (int t = 0; t < 4; ++t) {
        _Float16 h = (_Float16)f[t];
        H.u[t] = *reinterpret_cast<ushort_t*>(&h);
      }
      *reinterpret_cast<uint2*>(xh + (size_t)row * d + k) = H.v2;
    }
  }
#pragma unroll
  for (int off = 32; off > 0; off >>= 1) s += __shfl_down(s, off, 64);
  if (threadIdx.x == 0) sq[row] = s;
  if (row == 0 && threadIdx.x == 0) { *neg_total = 0.f; *neg_cnt = 0u; }
}

// ---------------- class-bucket build: hist -> scan -> scatter (1 block) -----
__launch_bounds__(1024)
__global__ void nl_bucket_kernel(const int* __restrict__ targets,
                                 int* __restrict__ cls_start, int* __restrict__ members,
                                 int n) {
  __shared__ int cnt[8192];
  __shared__ int aux[1024];
  const int tid = threadIdx.x;             // 1024 threads, n <= 8192
  for (int k = tid; k < n; k += 1024) cnt[k] = 0;
  __syncthreads();
  for (int k = tid; k < n; k += 1024) atomicAdd(&cnt[targets[k]], 1);
  __syncthreads();
  const int C = (n + 1023) / 1024;         // 8 for n=8192
  int v[8]; int s = 0;
  for (int e = 0; e < C; ++e) {
    int idx = tid * C + e;
    int t = (idx < n) ? cnt[idx] : 0;
    v[e] = s; s += t;
  }
  aux[tid] = s;
  __syncthreads();
  for (int off = 1; off < 1024; off <<= 1) {
    int t = (tid >= off) ? aux[tid - off] : 0;
    __syncthreads();
    aux[tid] += t;
    __syncthreads();
  }
  int chunk_excl = aux[tid] - s;
  __syncthreads();
  for (int e = 0; e < C; ++e) {
    int idx = tid * C + e;
    if (idx < n) {
      int st = chunk_excl + v[e];
      cls_start[idx] = st;
      cnt[idx] = st;
    }
  }
  __syncthreads();
  for (int k = tid; k < n; k += 1024) {
    int t = targets[k];
    int p = atomicAdd(&cnt[t], 1);
    members[p] = k;
  }
}

// ---------------- positives pass: one wave per CLASS (exact fp32) -----------
// Members cached in LDS once -> each row read exactly once (vs ~cnt times in
// the wave-per-point scheme). Pair dots: 8 FMA/lane + 6-shuffle butterfly.
// Fallback path (cnt>16 or d>512): per-pair global loads, still exact.
__launch_bounds__(64)
__global__ void nl_pos_class(const float* __restrict__ x, const float* __restrict__ sq,
                             const int* __restrict__ cls_start, const int* __restrict__ members,
                             float* __restrict__ min_pos, float* __restrict__ pos_sum,
                             int* __restrict__ pos_cnt,
                             float* __restrict__ sel_sum, int* __restrict__ sel_cnt,
                             int n, int d) {
  __shared__ float xr[16][512];
  __shared__ float mnL[16], sumL[16];
  const int c = blockIdx.x;
  const int s = cls_start[c];
  const int e = (c + 1 < n) ? cls_start[c + 1] : n;
  const int cnt = e - s;
  if (cnt <= 0) return;
  const int lane = threadIdx.x;            // 64 threads = 1 wave

  if (cnt <= 16 && d <= 512) {
    // ---- LDS-cached path ----
    for (int m = 0; m < cnt; ++m) {
      const float* row = x + (size_t)members[s + m] * d;
      for (int k = lane * 4; k < d; k += 256)
        *reinterpret_cast<float4*>(&xr[m][k]) = *reinterpret_cast<const float4*>(row + k);
    }
    if (lane < 16) { mnL[lane] = INFINITY; sumL[lane] = 0.f; }
    __builtin_amdgcn_s_barrier();
    for (int a = 0; a < cnt; ++a) {
      for (int b = a + 1; b < cnt; ++b) {
        float acc = 0.f;
        for (int k = lane * 4; k < d; k += 256) {
          float4 va = *reinterpret_cast<const float4*>(&xr[a][k]);
          float4 vb = *reinterpret_cast<const float4*>(&xr[b][k]);
          acc = fmaf(va.x, vb.x, acc); acc = fmaf(va.y, vb.y, acc);
          acc = fmaf(va.z, vb.z, acc); acc = fmaf(va.w, vb.w, acc);
        }
#pragma unroll
        for (int off = 32; off > 0; off >>= 1) acc += __shfl_xor(acc, off, 64);
        if (lane == 0) {
          int ia = members[s + a], ib = members[s + b];
          float d2 = sq[ia] + sq[ib] - 2.f * acc;
          float dist = sqrtf(fmaxf(d2, 1e-12f));
          mnL[a] = fminf(mnL[a], dist); sumL[a] += dist;
          mnL[b] = fminf(mnL[b], dist); sumL[b] += dist;
        }
      }
    }
    __builtin_amdgcn_s_barrier();
    for (int m = lane; m < cnt; m += 64) {
      int i = members[s + m];
      min_pos[i] = mnL[m]; pos_sum[i] = sumL[m]; pos_cnt[i] = cnt - 1;
      sel_sum[i] = 0.f; sel_cnt[i] = 0;
    }
  } else {
    // ---- fallback: per-member scan within the class (exact fp32) ----
    for (int a = 0; a < cnt; ++a) {
      int i = members[s + a];
      const float* xi = x + (size_t)i * d;
      float mn = INFINITY, sum = 0.f;
      for (int bm = 0; bm < cnt; ++bm) {
        if (bm == a) continue;
        int j = members[s + bm];
        const float* xj = x + (size_t)j * d;
        float acc = 0.f;
        for (int k = lane * 4; k < d; k += 256) {
          float4 va = *reinterpret_cast<const float4*>(xi + k);
          float4 vb = *reinterpret_cast<const float4*>(xj + k);
          acc = fmaf(va.x, vb.x, acc); acc = fmaf(va.y, vb.y, acc);
          acc = fmaf(va.z, vb.z, acc); acc = fmaf(va.w, vb.w, acc);
        }
#pragma unroll
        for (int off = 32; off > 0; off >>= 1) acc += __shfl_xor(acc, off, 64);
        float d2 = sq[i] + sq[j] - 2.f * acc;
        float dist = sqrtf(fmaxf(d2, 1e-12f));
        mn = fminf(mn, dist); sum += dist;
      }
      if (lane == 0) {
        min_pos[i] = mn; pos_sum[i] = sum; pos_cnt[i] = cnt - 1;
        sel_sum[i] = 0.f; sel_cnt[i] = 0;
      }
    }
  }
}

// ---------------- positives pass fallback: full scan (exact fp32) ------------
__launch_bounds__(256)
__global__ void nl_pos_scan(const float* __restrict__ x, const int* __restrict__ targets,
                            const float* __restrict__ sq,
                            float* __restrict__ min_pos, float* __restrict__ pos_sum,
                            int* __restrict__ pos_cnt,
                            float* __restrict__ sel_sum, int* __restrict__ sel_cnt,
                            int n, int d) {
  const int lane = threadIdx.x & 63;
  const int i = (blockIdx.x * blockDim.x + threadIdx.x) >> 6;
  if (i >= n) return;
  const int tgt = targets[i];
  const float sqi = sq[i];
  const float* xi = x + (size_t)i * d;
  float mn = INFINITY, sum = 0.f;
  int cnt = 0;
  for (int j0 = 0; j0 < n; j0 += 64) {
    int j = j0 + lane;
    bool match = (j < n) && (j != i) && (targets[j] == tgt);
    unsigned long long mask = __ballot(match);
    while (mask) {
      int b = __ffsll(mask) - 1;
      mask &= mask - 1;
      int jj = j0 + b;
      const float* xj = x + (size_t)jj * d;
      float acc = 0.f;
      for (int k = lane * 4; k < d; k += 256) {
        float4 a = *reinterpret_cast<const float4*>(xi + k);
        float4 v = *reinterpret_cast<const float4*>(xj + k);
        acc = fmaf(a.x, v.x, acc); acc = fmaf(a.y, v.y, acc);
        acc = fmaf(a.z, v.z, acc); acc = fmaf(a.w, v.w, acc);
      }
#pragma unroll
      for (int off = 32; off > 0; off >>= 1) acc += __shfl_down(acc, off, 64);
      if (lane == 0) {
        float d2 = sqi + sq[jj] - 2.f * acc;
        float dist = sqrtf(fmaxf(d2, 1e-12f));
        mn = fminf(mn, dist); sum += dist; cnt++;
      }
    }
  }
  if (lane == 0) {
    min_pos[i] = mn; pos_sum[i] = sum; pos_cnt[i] = cnt;
    sel_sum[i] = 0.f; sel_cnt[i] = 0;
  }
}

// ---------------- MFMA symmetric main sweep, f16, 8-wave / 6-per-SIMD -------
// 128x128 tile, 512 threads (8 waves, 2x4 grid, 64x32 per wave -> acc=32
// f32/lane). Single buffer: A,B panels of 128x32 f16 = 8KB each = 16 KB.
// Serial per block: {vmcnt(0); barrier; ds_read+MFMA; lgkmcnt(0); barrier;
// stage next}. Cross-block wave overlap hides staging (R11 mechanism) at
// 6 waves/SIMD. Read-side bank fix: 16B chunk index XOR'd with (row>>1)&3
// on the global SOURCE (global_load_lds writes linearly) and on the ds_read.
__device__ __forceinline__ void stage_tile512(const ushort_t* __restrict__ S, int r0, int k0,
                                              int ld, char* lds) {
  const int c = threadIdx.x;               // 512 chunks of 16B, one per thread
  int row = c >> 2;                        // 4 chunks per row
  int kc = (c & 3) ^ ((row >> 1) & 3);     // pre-swizzled source chunk
  const ushort_t* g = S + (size_t)(r0 + row) * ld + k0 + kc * 8;
  __builtin_amdgcn_global_load_lds(
      (const __attribute__((address_space(1))) unsigned int*)g,
      (__attribute__((address_space(3))) unsigned int*)(lds + c * 16),
      16, 0, 0);
}

__launch_bounds__(512, 6)
__global__ void nl_main_mfma(const ushort_t* __restrict__ xh,
                             const int* __restrict__ targets, const float* __restrict__ sq,
                             const float* __restrict__ min_pos,
                             float* __restrict__ sel_sum, int* __restrict__ sel_cnt,
                             float* __restrict__ neg_total, unsigned int* __restrict__ neg_cnt,
                             int n, int d) {
  __shared__ char smem[2][8192];           // [A,B]  16 KB single buffer
  __shared__ float red_sel[128];
  __shared__ int red_cnt[128];
  __shared__ float red_csel[128];
  __shared__ int red_ccnt[128];
  __shared__ float red_neg;
  __shared__ unsigned int red_negc;

  const int tid = threadIdx.x;
  const int lane = tid & 63;
  const int w = tid >> 6;                  // 8 waves
  const int wr = w >> 2, wc = w & 3;       // 2x4 wave grid, 64x32 per wave

  // XCD-bijective swizzle (m204 formula, valid for any grid size)
  const int nwg = gridDim.x;
  const int q8 = nwg >> 3, r8 = nwg & 7;
  const int xcd = blockIdx.x & 7, sub = blockIdx.x >> 3;
  const int wg = (xcd < r8 ? xcd * (q8 + 1) : r8 * (q8 + 1) + (xcd - r8) * q8) + sub;

  // triangular decode: wg -> (bi, bj), bi <= bj
  const int nbx = n >> 7;
  int tt = wg, bi = 0, len = nbx;
  while (tt >= len) { tt -= len; ++bi; --len; }
  const int bj = bi + tt;
  const int row0 = bi * 128, col0 = bj * 128;
  const bool isdiag = (bi == bj);

  if (tid < 128) { red_sel[tid] = 0.f; red_cnt[tid] = 0; red_csel[tid] = 0.f; red_ccnt[tid] = 0; }
  if (tid == 0) { red_neg = 0.f; red_negc = 0u; }

  f32x4 acc[4][2];
#pragma unroll
  for (int m = 0; m < 4; ++m)
#pragma unroll
    for (int nn = 0; nn < 2; ++nn) acc[m][nn] = (f32x4){0.f, 0.f, 0.f, 0.f};

  const int TOT = d >> 5;                  // k-tiles (16)

  // prologue: stage both panels of k-tile 0 (2 loads/thread)
  stage_tile512(xh, row0, 0, d, smem[0]);
  stage_tile512(xh, col0, 0, d, smem[1]);

  const int r = lane & 15;
  const int g = lane >> 4;
  const int chunk = (g ^ ((r >> 1) & 3)) * 16;

  for (int kt = 0; kt < TOT; ++kt) {
    asm volatile("s_waitcnt vmcnt(0)" ::: "memory");   // own loads landed
    __builtin_amdgcn_s_barrier();                      // all waves' loads landed
    __builtin_amdgcn_sched_barrier(0);

    f16x8 a[4], b[2];
#pragma unroll
    for (int m = 0; m < 4; ++m)
      a[m] = *reinterpret_cast<const f16x8*>(smem[0] + (wr * 64 + m * 16 + r) * 64 + chunk);
#pragma unroll
    for (int nn = 0; nn < 2; ++nn)
      b[nn] = *reinterpret_cast<const f16x8*>(smem[1] + (wc * 32 + nn * 16 + r) * 64 + chunk);
#pragma unroll
    for (int m = 0; m < 4; ++m)
#pragma unroll
      for (int nn = 0; nn < 2; ++nn)
        acc[m][nn] = __builtin_amdgcn_mfma_f32_16x16x32_f16(a[m], b[nn], acc[m][nn], 0, 0, 0);

    if (kt + 1 < TOT) {
      asm volatile("s_waitcnt lgkmcnt(0)" ::: "memory");  // all ds_reads complete
      __builtin_amdgcn_s_barrier();                       // every wave done reading
      __builtin_amdgcn_sched_barrier(0);
      int k0 = (kt + 1) << 5;
      stage_tile512(xh, row0, k0, d, smem[0]);
      stage_tile512(xh, col0, k0, d, smem[1]);
    }
  }

  // ---- epilogue: dist + masks + row AND col partials ----
  // C/D layout (m89-verified, dtype-independent): col = lane&15, row = (lane>>4)*4 + reg
  const int col_base = col0 + wc * 32;
  float sqj[2], thrj[2];
  int tgtj[2];
#pragma unroll
  for (int nn = 0; nn < 2; ++nn) {
    int gc = col_base + nn * 16 + (lane & 15);
    sqj[nn] = sq[gc];
    tgtj[nn] = targets[gc];
    thrj[nn] = min_pos[gc] + MARGIN_F;
  }
  float negsum = 0.f;
  unsigned int negc = 0u;
  float colsum[2] = {0.f, 0.f};
  int colcnt[2] = {0, 0};
#pragma unroll
  for (int m = 0; m < 4; ++m) {
#pragma unroll
    for (int reg = 0; reg < 4; ++reg) {
      int lrow = wr * 64 + m * 16 + (lane >> 4) * 4 + reg;
      int gr = row0 + lrow;
      float sqi = sq[gr];
      int tgti = targets[gr];
      float thr = min_pos[gr] + MARGIN_F;
      float rs = 0.f; int rc = 0;
#pragma unroll
      for (int nn = 0; nn < 2; ++nn) {
        float d2 = sqi + sqj[nn] - 2.f * acc[m][nn][reg];
        float dist = sqrtf(fmaxf(d2, 1e-12f));
        if (tgti != tgtj[nn]) {
          negsum += dist; negc++;
          if (dist < thr) { rc++; rs += dist; }
          if (!isdiag && dist < thrj[nn]) { colcnt[nn]++; colsum[nn] += dist; }
        }
      }
      // reduce across the 16 lanes that share this row
#pragma unroll
      for (int off = 1; off < 16; off <<= 1) {
        rs += __shfl_xor(rs, off, 64);
        rc += __shfl_xor(rc, off, 64);
      }
      if ((lane & 15) == 0) {
        atomicAdd(&red_cnt[lrow], rc);
        atomicAdd(&red_sel[lrow], rs);
      }
    }
  }
  if (!isdiag) {
    // col partials: same column for all (m,reg); reduce across lane>>4 groups
#pragma unroll
    for (int nn = 0; nn < 2; ++nn) {
      float cs = colsum[nn]; int cc = colcnt[nn];
      cs += __shfl_xor(cs, 16, 64); cc += __shfl_xor(cc, 16, 64);
      cs += __shfl_xor(cs, 32, 64); cc += __shfl_xor(cc, 32, 64);
      if ((lane >> 4) == 0 && cc) {
        int lcol = wc * 32 + nn * 16 + lane;
        atomicAdd(&red_ccnt[lcol], cc);
        atomicAdd(&red_csel[lcol], cs);
      }
    }
    negsum *= 2.f; negc *= 2u;             // both ordered pairs
  }
#pragma unroll
  for (int off = 32; off > 0; off >>= 1) {
    negsum += __shfl_down(negsum, off, 64);
    negc += __shfl_down(negc, off, 64);
  }
  if (lane == 0) { atomicAdd(&red_neg, negsum); atomicAdd(&red_negc, negc); }
  __syncthreads();
  if (tid < 128) {
    int c = red_cnt[tid];
    if (c > 0) {
      atomicAdd(&sel_cnt[row0 + tid], c);
      atomicAdd(&sel_sum[row0 + tid], red_sel[tid]);
    }
    if (!isdiag) {
      int c2 = red_ccnt[tid];
      if (c2 > 0) {
        atomicAdd(&sel_cnt[col0 + tid], c2);
        atomicAdd(&sel_sum[col0 + tid], red_csel[tid]);
      }
    }
  }
  if (tid == 0) { atomicAdd(neg_total, red_neg); atomicAdd(neg_cnt, red_negc); }
}

// ---------------- fp32 fallback main sweep (if ws too small) ----------------
#define BM 128
#define BN 128
#define BK 16
#define PAD 4
__launch_bounds__(256)
__global__ void nl_main_kernel(const float* __restrict__ x, const int* __restrict__ targets,
                               const float* __restrict__ sq, const float* __restrict__ min_pos,
                               float* __restrict__ sel_sum, int* __restrict__ sel_cnt,
                               float* __restrict__ neg_total, unsigned int* __restrict__ neg_cnt,
                               int n, int d) {
  __shared__ float As[BK][BM + PAD];
  __shared__ float Bs[BK][BN + PAD];
  __shared__ float red_sel[BM];
  __shared__ int red_cnt[BM];
  __shared__ float red_neg;
  __shared__ unsigned int red_negc;

  const int tid = threadIdx.x;
  const int tx = tid & 15;
  const int ty = tid >> 4;
  const int row0 = blockIdx.y * BM;
  const int col0 = blockIdx.x * BN;

  if (tid < BM) { red_sel[tid] = 0.f; red_cnt[tid] = 0; }
  if (tid == 0) { red_neg = 0.f; red_negc = 0u; }

  float acc[8][8];
#pragma unroll
  for (int i = 0; i < 8; ++i)
#pragma unroll
    for (int j = 0; j < 8; ++j) acc[i][j] = 0.f;

  const int lr = tid >> 2;
  const int lk = (tid & 3) << 2;

  for (int k0 = 0; k0 < d; k0 += BK) {
    float4 va0 = *reinterpret_cast<const float4*>(x + (size_t)(row0 + lr) * d + k0 + lk);
    float4 va1 = *reinterpret_cast<const float4*>(x + (size_t)(row0 + lr + 64) * d + k0 + lk);
    float4 vb0 = *reinterpret_cast<const float4*>(x + (size_t)(col0 + lr) * d + k0 + lk);
    float4 vb1 = *reinterpret_cast<const float4*>(x + (size_t)(col0 + lr + 64) * d + k0 + lk);
    __syncthreads();
    As[lk + 0][lr] = va0.x; As[lk + 1][lr] = va0.y; As[lk + 2][lr] = va0.z; As[lk + 3][lr] = va0.w;
    As[lk + 0][lr + 64] = va1.x; As[lk + 1][lr + 64] = va1.y; As[lk + 2][lr + 64] = va1.z; As[lk + 3][lr + 64] = va1.w;
    Bs[lk + 0][lr] = vb0.x; Bs[lk + 1][lr] = vb0.y; Bs[lk + 2][lr] = vb0.z; Bs[lk + 3][lr] = vb0.w;
    Bs[lk + 0][lr + 64] = vb1.x; Bs[lk + 1][lr + 64] = vb1.y; Bs[lk + 2][lr + 64] = vb1.z; Bs[lk + 3][lr + 64] = vb1.w;
    __syncthreads();
#pragma unroll
    for (int k = 0; k < BK; ++k) {
      float a[8], b[8];
      *reinterpret_cast<float4*>(&a[0]) = *reinterpret_cast<const float4*>(&As[k][ty * 4]);
      *reinterpret_cast<float4*>(&a[4]) = *reinterpret_cast<const float4*>(&As[k][ty * 4 + 64]);
      *reinterpret_cast<float4*>(&b[0]) = *reinterpret_cast<const float4*>(&Bs[k][tx * 4]);
      *reinterpret_cast<float4*>(&b[4]) = *reinterpret_cast<const float4*>(&Bs[k][tx * 4 + 64]);
#pragma unroll
      for (int mm = 0; mm < 8; ++mm)
#pragma unroll
        for (int nn = 0; nn < 8; ++nn)
          acc[mm][nn] = fmaf(a[mm], b[nn], acc[mm][nn]);
    }
  }

  float sqj[8]; int tgtj[8];
#pragma unroll
  for (int nn = 0; nn < 8; ++nn) {
    int lc = tx * 4 + (nn & 3) + ((nn >> 2) << 6);
    sqj[nn] = sq[col0 + lc];
    tgtj[nn] = targets[col0 + lc];
  }
  float negsum = 0.f;
  unsigned int negc = 0u;
#pragma unroll
  for (int mm = 0; mm < 8; ++mm) {
    int lrow = ty * 4 + (mm & 3) + ((mm >> 2) << 6);
    int gi = row0 + lrow;
    float sqi = sq[gi];
    int tgti = targets[gi];
    float thr = min_pos[gi] + MARGIN_F;
    float rs = 0.f; int rc = 0;
#pragma unroll
    for (int nn = 0; nn < 8; ++nn) {
      float d2 = sqi + sqj[nn] - 2.f * acc[mm][nn];
      float dist = sqrtf(fmaxf(d2, 1e-12f));
      if (tgti != tgtj[nn]) {
        negsum += dist; negc++;
        if (dist < thr) { rc++; rs += dist; }
      }
    }
    if (rc) { atomicAdd(&red_cnt[lrow], rc); atomicAdd(&red_sel[lrow], rs); }
  }
#pragma unroll
  for (int off = 32; off > 0; off >>= 1) {
    negsum += __shfl_down(negsum, off, 64);
    negc += __shfl_down(negc, off, 64);
  }
  if ((tid & 63) == 0) { atomicAdd(&red_neg, negsum); atomicAdd(&red_negc, negc); }
  __syncthreads();
  if (tid < BM && red_cnt[tid] > 0) {
    atomicAdd(&sel_cnt[row0 + tid], red_cnt[tid]);
    atomicAdd(&sel_sum[row0 + tid], red_sel[tid]);
  }
  if (tid == 0) { atomicAdd(neg_total, red_neg); atomicAdd(neg_cnt, red_negc); }
}

// ---------------- finalize: 4 scalars ----------------
__global__ void nl_finalize(const float* __restrict__ min_pos, const float* __restrict__ pos_sum,
                            const int* __restrict__ pos_cnt, const float* __restrict__ sel_sum,
                            const int* __restrict__ sel_cnt, const float* __restrict__ neg_total,
                            const unsigned int* __restrict__ neg_cnt, float* __restrict__ out,
                            int n) {
  const int tid = threadIdx.x;
  float loss = 0.f, psum = 0.f;
  int nvalid = 0, pcnt = 0;
  for (int i = tid; i < n; i += 256) {
    int c = sel_cnt[i];
    if (c > 0) {
      float mean_neg = sel_sum[i] / (float)c;
      loss += min_pos[i] - mean_neg + MARGIN_F;
      nvalid++;
    }
    psum += pos_sum[i];
    pcnt += pos_cnt[i];
  }
  __shared__ float s_loss[256];
  __shared__ float s_psum[256];
  __shared__ int s_nv[256];
  __shared__ int s_pc[256];
  s_loss[tid] = loss; s_psum[tid] = psum; s_nv[tid] = nvalid; s_pc[tid] = pcnt;
  __syncthreads();
  for (int s = 128; s > 0; s >>= 1) {
    if (tid < s) {
      s_loss[tid] += s_loss[tid + s];
      s_psum[tid] += s_psum[tid + s];
      s_nv[tid] += s_nv[tid + s];
      s_pc[tid] += s_pc[tid + s];
    }
    __syncthreads();
  }
  if (tid == 0) {
    out[0] = s_loss[0] / (float)n;
    out[1] = 1.f - (float)s_nv[0] / (float)n;
    out[2] = s_psum[0] / (float)s_pc[0];
    out[3] = neg_total[0] / (float)neg_cnt[0];
  }
}

extern "C" void kernel_launch(void* const* d_in, const int* in_sizes, int n_in,
                              void* d_out, int out_size, void* d_ws, size_t ws_size,
                              hipStream_t stream) {
  const float* x = (const float*)d_in[0];
  const int* targets = (const int*)d_in[1];
  float* out = (float*)d_out;
  const int n = in_sizes[1];
  const int d = in_sizes[0] / n;

  // ws layout: stats block (8n+2 words), then (256B-aligned) f16 array
  float* sq = (float*)d_ws;
  float* min_pos = sq + n;
  float* pos_sum = min_pos + n;
  int* pos_cnt = (int*)(pos_sum + n);
  float* sel_sum = (float*)(pos_cnt + n);
  int* sel_cnt = (int*)(sel_sum + n);
  int* cls_start = (int*)(sel_cnt + n);
  int* members = cls_start + n;
  float* neg_total = (float*)(members + n);
  unsigned int* neg_cnt = (unsigned int*)(neg_total + 1);
  size_t stats_bytes = ((size_t)(8 * n + 2) * 4 + 255) & ~(size_t)255;
  ushort_t* xh = (ushort_t*)((char*)d_ws + stats_bytes);
  size_t need = stats_bytes + (size_t)n * d * sizeof(ushort_t);

  const bool mfma_ok = (ws_size >= need) && (n % 128) == 0 && (d % 32) == 0;
  const bool bucket_ok = (ws_size >= stats_bytes) && (n <= 8192) && (d % 16) == 0;

  nl_prep_kernel<<<dim3((n + 3) / 4), dim3(64, 4), 0, stream>>>(
      x, sq, mfma_ok ? xh : nullptr, neg_total, neg_cnt, n, d);
  if (bucket_ok) {
    nl_bucket_kernel<<<1, 1024, 0, stream>>>(targets, cls_start, members, n);
    nl_pos_class<<<n, 64, 0, stream>>>(
        x, sq, cls_start, members, min_pos, pos_sum, pos_cnt, sel_sum, sel_cnt, n, d);
  } else {
    nl_pos_scan<<<(n * 64 + 255) / 256, 256, 0, stream>>>(
        x, targets, sq, min_pos, pos_sum, pos_cnt, sel_sum, sel_cnt, n, d);
  }

  if (mfma_ok) {
    int nbx = n / 128;
    int ntiles = nbx * (nbx + 1) / 2;
    nl_main_mfma<<<ntiles, 512, 0, stream>>>(xh, targets, sq, min_pos, sel_sum,
                                             sel_cnt, neg_total, neg_cnt, n, d);
  } else {
    nl_main_kernel<<<dim3(n / BN, n / BM), 256, 0, stream>>>(x, targets, sq, min_pos, sel_sum,
                                                             sel_cnt, neg_total, neg_cnt, n, d);
  }
  nl_finalize<<<1, 256, 0, stream>>>(min_pos, pos_sum, pos_cnt, sel_sum, sel_cnt,
                                     neg_total, neg_cnt, out, n);
}

// Round 19
// 161.379 us; speedup vs baseline: 1.0964x; 1.0964x over previous
//
#include <hip/hip_runtime.h>
#include <hip/hip_bf16.h>
#include <math.h>

// NeighbourLoss: n=8192 pts, d=512, n_classes=1024 (8/class -> 7 positives/row).
// Outputs: loss, prec, pos_d, neg_d (4 floats).
// Pipeline: prep (sq + f16 convert) -> class-bucket build -> bucketed exact
// fp32 positive pass (thresh exact) -> symmetric MFMA Gram sweep (single f16
// product), 128x128 triangular tiles, 512 threads / 8 waves (64x32 per wave:
// acc=32 f32/lane -> 6 waves/SIMD), single 16KB LDS buffer, serial
// stage-then-compute (R17 config, measured best: 161.5us total) -> finalize.
// Assumes n % 128 == 0, d % 32 == 0, n <= 8192.

#define MARGIN_F 0.1f

typedef unsigned short ushort_t;
typedef __attribute__((ext_vector_type(8))) _Float16 f16x8;
typedef __attribute__((ext_vector_type(4))) float f32x4;

// ---------------- prep: row squared norms + f16 convert ----------------
__global__ void nl_prep_kernel(const float* __restrict__ x, float* __restrict__ sq,
                               ushort_t* __restrict__ xh,
                               float* __restrict__ neg_total, unsigned int* __restrict__ neg_cnt,
                               int n, int d) {
  int row = blockIdx.x * blockDim.y + threadIdx.y;   // blockDim = (64,4)
  if (row >= n) return;
  const float* xr = x + (size_t)row * d;
  float s = 0.f;
  for (int k = threadIdx.x * 4; k < d; k += 64 * 4) {
    float4 v = *reinterpret_cast<const float4*>(xr + k);
    s = fmaf(v.x, v.x, s); s = fmaf(v.y, v.y, s);
    s = fmaf(v.z, v.z, s); s = fmaf(v.w, v.w, s);
    if (xh != nullptr) {
      float f[4] = {v.x, v.y, v.z, v.w};
      union { ushort_t u[4]; uint2 v2; } H;
#pragma unroll
      for (int t = 0; t < 4; ++t) {
        _Float16 h = (_Float16)f[t];
        H.u[t] = *reinterpret_cast<ushort_t*>(&h);
      }
      *reinterpret_cast<uint2*>(xh + (size_t)row * d + k) = H.v2;
    }
  }
#pragma unroll
  for (int off = 32; off > 0; off >>= 1) s += __shfl_down(s, off, 64);
  if (threadIdx.x == 0) sq[row] = s;
  if (row == 0 && threadIdx.x == 0) { *neg_total = 0.f; *neg_cnt = 0u; }
}

// ---------------- class-bucket build: hist -> scan -> scatter (1 block) -----
__launch_bounds__(1024)
__global__ void nl_bucket_kernel(const int* __restrict__ targets,
                                 int* __restrict__ cls_start, int* __restrict__ members,
                                 int n) {
  __shared__ int cnt[8192];
  __shared__ int aux[1024];
  const int tid = threadIdx.x;             // 1024 threads, n <= 8192
  for (int k = tid; k < n; k += 1024) cnt[k] = 0;
  __syncthreads();
  for (int k = tid; k < n; k += 1024) atomicAdd(&cnt[targets[k]], 1);
  __syncthreads();
  const int C = (n + 1023) / 1024;         // 8 for n=8192
  int v[8]; int s = 0;
  for (int e = 0; e < C; ++e) {
    int idx = tid * C + e;
    int t = (idx < n) ? cnt[idx] : 0;
    v[e] = s; s += t;
  }
  aux[tid] = s;
  __syncthreads();
  for (int off = 1; off < 1024; off <<= 1) {
    int t = (tid >= off) ? aux[tid - off] : 0;
    __syncthreads();
    aux[tid] += t;
    __syncthreads();
  }
  int chunk_excl = aux[tid] - s;
  __syncthreads();
  for (int e = 0; e < C; ++e) {
    int idx = tid * C + e;
    if (idx < n) {
      int st = chunk_excl + v[e];
      cls_start[idx] = st;
      cnt[idx] = st;
    }
  }
  __syncthreads();
  for (int k = tid; k < n; k += 1024) {
    int t = targets[k];
    int p = atomicAdd(&cnt[t], 1);
    members[p] = k;
  }
}

// ---------------- positives pass: one wave per point, bucketed (exact fp32) --
__launch_bounds__(256)
__global__ void nl_pos_bucket(const float* __restrict__ x, const int* __restrict__ targets,
                              const float* __restrict__ sq,
                              const int* __restrict__ cls_start, const int* __restrict__ members,
                              float* __restrict__ min_pos, float* __restrict__ pos_sum,
                              int* __restrict__ pos_cnt,
                              float* __restrict__ sel_sum, int* __restrict__ sel_cnt,
                              int n, int d) {
  const int lane = threadIdx.x & 63;
  const int i = (blockIdx.x * blockDim.x + threadIdx.x) >> 6;
  if (i >= n) return;
  const int tgt = targets[i];
  const float sqi = sq[i];
  const float* xi = x + (size_t)i * d;
  float4 xreg[2];
  const int k0 = lane * 4;
#pragma unroll
  for (int c = 0; c < 2; ++c)
    if (k0 + c * 256 < d) xreg[c] = *reinterpret_cast<const float4*>(xi + k0 + c * 256);
  const int s = cls_start[tgt];
  const int e = (tgt + 1 < n) ? cls_start[tgt + 1] : n;
  float mn = INFINITY, sum = 0.f;
  int cnt = 0;
  for (int mi = s; mi < e; ++mi) {
    int j = members[mi];
    if (j == i) continue;
    const float* xj = x + (size_t)j * d;
    float acc = 0.f;
    if (d == 512) {
      float4 a0 = xreg[0], a1 = xreg[1];
      float4 v0 = *reinterpret_cast<const float4*>(xj + k0);
      float4 v1 = *reinterpret_cast<const float4*>(xj + k0 + 256);
      acc = fmaf(a0.x, v0.x, acc); acc = fmaf(a0.y, v0.y, acc);
      acc = fmaf(a0.z, v0.z, acc); acc = fmaf(a0.w, v0.w, acc);
      acc = fmaf(a1.x, v1.x, acc); acc = fmaf(a1.y, v1.y, acc);
      acc = fmaf(a1.z, v1.z, acc); acc = fmaf(a1.w, v1.w, acc);
    } else {
      for (int k = k0; k < d; k += 256) {
        float4 a = *reinterpret_cast<const float4*>(xi + k);
        float4 v = *reinterpret_cast<const float4*>(xj + k);
        acc = fmaf(a.x, v.x, acc); acc = fmaf(a.y, v.y, acc);
        acc = fmaf(a.z, v.z, acc); acc = fmaf(a.w, v.w, acc);
      }
    }
#pragma unroll
    for (int off = 32; off > 0; off >>= 1) acc += __shfl_down(acc, off, 64);
    if (lane == 0) {
      float d2 = sqi + sq[j] - 2.f * acc;
      float dist = sqrtf(fmaxf(d2, 1e-12f));
      mn = fminf(mn, dist); sum += dist; cnt++;
    }
  }
  if (lane == 0) {
    min_pos[i] = mn; pos_sum[i] = sum; pos_cnt[i] = cnt;
    sel_sum[i] = 0.f; sel_cnt[i] = 0;
  }
}

// ---------------- positives pass fallback: full scan (exact fp32) ------------
__launch_bounds__(256)
__global__ void nl_pos_scan(const float* __restrict__ x, const int* __restrict__ targets,
                            const float* __restrict__ sq,
                            float* __restrict__ min_pos, float* __restrict__ pos_sum,
                            int* __restrict__ pos_cnt,
                            float* __restrict__ sel_sum, int* __restrict__ sel_cnt,
                            int n, int d) {
  const int lane = threadIdx.x & 63;
  const int i = (blockIdx.x * blockDim.x + threadIdx.x) >> 6;
  if (i >= n) return;
  const int tgt = targets[i];
  const float sqi = sq[i];
  const float* xi = x + (size_t)i * d;
  float mn = INFINITY, sum = 0.f;
  int cnt = 0;
  for (int j0 = 0; j0 < n; j0 += 64) {
    int j = j0 + lane;
    bool match = (j < n) && (j != i) && (targets[j] == tgt);
    unsigned long long mask = __ballot(match);
    while (mask) {
      int b = __ffsll(mask) - 1;
      mask &= mask - 1;
      int jj = j0 + b;
      const float* xj = x + (size_t)jj * d;
      float acc = 0.f;
      for (int k = lane * 4; k < d; k += 256) {
        float4 a = *reinterpret_cast<const float4*>(xi + k);
        float4 v = *reinterpret_cast<const float4*>(xj + k);
        acc = fmaf(a.x, v.x, acc); acc = fmaf(a.y, v.y, acc);
        acc = fmaf(a.z, v.z, acc); acc = fmaf(a.w, v.w, acc);
      }
#pragma unroll
      for (int off = 32; off > 0; off >>= 1) acc += __shfl_down(acc, off, 64);
      if (lane == 0) {
        float d2 = sqi + sq[jj] - 2.f * acc;
        float dist = sqrtf(fmaxf(d2, 1e-12f));
        mn = fminf(mn, dist); sum += dist; cnt++;
      }
    }
  }
  if (lane == 0) {
    min_pos[i] = mn; pos_sum[i] = sum; pos_cnt[i] = cnt;
    sel_sum[i] = 0.f; sel_cnt[i] = 0;
  }
}

// ---------------- MFMA symmetric main sweep, f16, 8-wave / 6-per-SIMD -------
// 128x128 tile, 512 threads (8 waves, 2x4 grid, 64x32 per wave -> acc=32
// f32/lane). Single buffer: A,B panels of 128x32 f16 = 8KB each = 16 KB.
// Serial per block: {vmcnt(0); barrier; ds_read+MFMA; lgkmcnt(0); barrier;
// stage next}. Cross-block wave overlap hides staging (R11 mechanism) at
// 6 waves/SIMD. Read-side bank fix: 16B chunk index XOR'd with (row>>1)&3
// on the global SOURCE (global_load_lds writes linearly) and on the ds_read.
__device__ __forceinline__ void stage_tile512(const ushort_t* __restrict__ S, int r0, int k0,
                                              int ld, char* lds) {
  const int c = threadIdx.x;               // 512 chunks of 16B, one per thread
  int row = c >> 2;                        // 4 chunks per row
  int kc = (c & 3) ^ ((row >> 1) & 3);     // pre-swizzled source chunk
  const ushort_t* g = S + (size_t)(r0 + row) * ld + k0 + kc * 8;
  __builtin_amdgcn_global_load_lds(
      (const __attribute__((address_space(1))) unsigned int*)g,
      (__attribute__((address_space(3))) unsigned int*)(lds + c * 16),
      16, 0, 0);
}

__launch_bounds__(512, 6)
__global__ void nl_main_mfma(const ushort_t* __restrict__ xh,
                             const int* __restrict__ targets, const float* __restrict__ sq,
                             const float* __restrict__ min_pos,
                             float* __restrict__ sel_sum, int* __restrict__ sel_cnt,
                             float* __restrict__ neg_total, unsigned int* __restrict__ neg_cnt,
                             int n, int d) {
  __shared__ char smem[2][8192];           // [A,B]  16 KB single buffer
  __shared__ float red_sel[128];
  __shared__ int red_cnt[128];
  __shared__ float red_csel[128];
  __shared__ int red_ccnt[128];
  __shared__ float red_neg;
  __shared__ unsigned int red_negc;

  const int tid = threadIdx.x;
  const int lane = tid & 63;
  const int w = tid >> 6;                  // 8 waves
  const int wr = w >> 2, wc = w & 3;       // 2x4 wave grid, 64x32 per wave

  // XCD-bijective swizzle (m204 formula, valid for any grid size)
  const int nwg = gridDim.x;
  const int q8 = nwg >> 3, r8 = nwg & 7;
  const int xcd = blockIdx.x & 7, sub = blockIdx.x >> 3;
  const int wg = (xcd < r8 ? xcd * (q8 + 1) : r8 * (q8 + 1) + (xcd - r8) * q8) + sub;

  // triangular decode: wg -> (bi, bj), bi <= bj
  const int nbx = n >> 7;
  int tt = wg, bi = 0, len = nbx;
  while (tt >= len) { tt -= len; ++bi; --len; }
  const int bj = bi + tt;
  const int row0 = bi * 128, col0 = bj * 128;
  const bool isdiag = (bi == bj);

  if (tid < 128) { red_sel[tid] = 0.f; red_cnt[tid] = 0; red_csel[tid] = 0.f; red_ccnt[tid] = 0; }
  if (tid == 0) { red_neg = 0.f; red_negc = 0u; }

  f32x4 acc[4][2];
#pragma unroll
  for (int m = 0; m < 4; ++m)
#pragma unroll
    for (int nn = 0; nn < 2; ++nn) acc[m][nn] = (f32x4){0.f, 0.f, 0.f, 0.f};

  const int TOT = d >> 5;                  // k-tiles (16)

  // prologue: stage both panels of k-tile 0 (2 loads/thread)
  stage_tile512(xh, row0, 0, d, smem[0]);
  stage_tile512(xh, col0, 0, d, smem[1]);

  const int r = lane & 15;
  const int g = lane >> 4;
  const int chunk = (g ^ ((r >> 1) & 3)) * 16;

  for (int kt = 0; kt < TOT; ++kt) {
    asm volatile("s_waitcnt vmcnt(0)" ::: "memory");   // own loads landed
    __builtin_amdgcn_s_barrier();                      // all waves' loads landed
    __builtin_amdgcn_sched_barrier(0);

    f16x8 a[4], b[2];
#pragma unroll
    for (int m = 0; m < 4; ++m)
      a[m] = *reinterpret_cast<const f16x8*>(smem[0] + (wr * 64 + m * 16 + r) * 64 + chunk);
#pragma unroll
    for (int nn = 0; nn < 2; ++nn)
      b[nn] = *reinterpret_cast<const f16x8*>(smem[1] + (wc * 32 + nn * 16 + r) * 64 + chunk);
#pragma unroll
    for (int m = 0; m < 4; ++m)
#pragma unroll
      for (int nn = 0; nn < 2; ++nn)
        acc[m][nn] = __builtin_amdgcn_mfma_f32_16x16x32_f16(a[m], b[nn], acc[m][nn], 0, 0, 0);

    if (kt + 1 < TOT) {
      asm volatile("s_waitcnt lgkmcnt(0)" ::: "memory");  // all ds_reads complete
      __builtin_amdgcn_s_barrier();                       // every wave done reading
      __builtin_amdgcn_sched_barrier(0);
      int k0 = (kt + 1) << 5;
      stage_tile512(xh, row0, k0, d, smem[0]);
      stage_tile512(xh, col0, k0, d, smem[1]);
    }
  }

  // ---- epilogue: dist + masks + row AND col partials ----
  // C/D layout (m89-verified, dtype-independent): col = lane&15, row = (lane>>4)*4 + reg
  const int col_base = col0 + wc * 32;
  float sqj[2], thrj[2];
  int tgtj[2];
#pragma unroll
  for (int nn = 0; nn < 2; ++nn) {
    int gc = col_base + nn * 16 + (lane & 15);
    sqj[nn] = sq[gc];
    tgtj[nn] = targets[gc];
    thrj[nn] = min_pos[gc] + MARGIN_F;
  }
  float negsum = 0.f;
  unsigned int negc = 0u;
  float colsum[2] = {0.f, 0.f};
  int colcnt[2] = {0, 0};
#pragma unroll
  for (int m = 0; m < 4; ++m) {
#pragma unroll
    for (int reg = 0; reg < 4; ++reg) {
      int lrow = wr * 64 + m * 16 + (lane >> 4) * 4 + reg;
      int gr = row0 + lrow;
      float sqi = sq[gr];
      int tgti = targets[gr];
      float thr = min_pos[gr] + MARGIN_F;
      float rs = 0.f; int rc = 0;
#pragma unroll
      for (int nn = 0; nn < 2; ++nn) {
        float d2 = sqi + sqj[nn] - 2.f * acc[m][nn][reg];
        float dist = sqrtf(fmaxf(d2, 1e-12f));
        if (tgti != tgtj[nn]) {
          negsum += dist; negc++;
          if (dist < thr) { rc++; rs += dist; }
          if (!isdiag && dist < thrj[nn]) { colcnt[nn]++; colsum[nn] += dist; }
        }
      }
      // reduce across the 16 lanes that share this row
#pragma unroll
      for (int off = 1; off < 16; off <<= 1) {
        rs += __shfl_xor(rs, off, 64);
        rc += __shfl_xor(rc, off, 64);
      }
      if ((lane & 15) == 0) {
        atomicAdd(&red_cnt[lrow], rc);
        atomicAdd(&red_sel[lrow], rs);
      }
    }
  }
  if (!isdiag) {
    // col partials: same column for all (m,reg); reduce across lane>>4 groups
#pragma unroll
    for (int nn = 0; nn < 2; ++nn) {
      float cs = colsum[nn]; int cc = colcnt[nn];
      cs += __shfl_xor(cs, 16, 64); cc += __shfl_xor(cc, 16, 64);
      cs += __shfl_xor(cs, 32, 64); cc += __shfl_xor(cc, 32, 64);
      if ((lane >> 4) == 0 && cc) {
        int lcol = wc * 32 + nn * 16 + lane;
        atomicAdd(&red_ccnt[lcol], cc);
        atomicAdd(&red_csel[lcol], cs);
      }
    }
    negsum *= 2.f; negc *= 2u;             // both ordered pairs
  }
#pragma unroll
  for (int off = 32; off > 0; off >>= 1) {
    negsum += __shfl_down(negsum, off, 64);
    negc += __shfl_down(negc, off, 64);
  }
  if (lane == 0) { atomicAdd(&red_neg, negsum); atomicAdd(&red_negc, negc); }
  __syncthreads();
  if (tid < 128) {
    int c = red_cnt[tid];
    if (c > 0) {
      atomicAdd(&sel_cnt[row0 + tid], c);
      atomicAdd(&sel_sum[row0 + tid], red_sel[tid]);
    }
    if (!isdiag) {
      int c2 = red_ccnt[tid];
      if (c2 > 0) {
        atomicAdd(&sel_cnt[col0 + tid], c2);
        atomicAdd(&sel_sum[col0 + tid], red_csel[tid]);
      }
    }
  }
  if (tid == 0) { atomicAdd(neg_total, red_neg); atomicAdd(neg_cnt, red_negc); }
}

// ---------------- fp32 fallback main sweep (if ws too small) ----------------
#define BM 128
#define BN 128
#define BK 16
#define PAD 4
__launch_bounds__(256)
__global__ void nl_main_kernel(const float* __restrict__ x, const int* __restrict__ targets,
                               const float* __restrict__ sq, const float* __restrict__ min_pos,
                               float* __restrict__ sel_sum, int* __restrict__ sel_cnt,
                               float* __restrict__ neg_total, unsigned int* __restrict__ neg_cnt,
                               int n, int d) {
  __shared__ float As[BK][BM + PAD];
  __shared__ float Bs[BK][BN + PAD];
  __shared__ float red_sel[BM];
  __shared__ int red_cnt[BM];
  __shared__ float red_neg;
  __shared__ unsigned int red_negc;

  const int tid = threadIdx.x;
  const int tx = tid & 15;
  const int ty = tid >> 4;
  const int row0 = blockIdx.y * BM;
  const int col0 = blockIdx.x * BN;

  if (tid < BM) { red_sel[tid] = 0.f; red_cnt[tid] = 0; }
  if (tid == 0) { red_neg = 0.f; red_negc = 0u; }

  float acc[8][8];
#pragma unroll
  for (int i = 0; i < 8; ++i)
#pragma unroll
    for (int j = 0; j < 8; ++j) acc[i][j] = 0.f;

  const int lr = tid >> 2;
  const int lk = (tid & 3) << 2;

  for (int k0 = 0; k0 < d; k0 += BK) {
    float4 va0 = *reinterpret_cast<const float4*>(x + (size_t)(row0 + lr) * d + k0 + lk);
    float4 va1 = *reinterpret_cast<const float4*>(x + (size_t)(row0 + lr + 64) * d + k0 + lk);
    float4 vb0 = *reinterpret_cast<const float4*>(x + (size_t)(col0 + lr) * d + k0 + lk);
    float4 vb1 = *reinterpret_cast<const float4*>(x + (size_t)(col0 + lr + 64) * d + k0 + lk);
    __syncthreads();
    As[lk + 0][lr] = va0.x; As[lk + 1][lr] = va0.y; As[lk + 2][lr] = va0.z; As[lk + 3][lr] = va0.w;
    As[lk + 0][lr + 64] = va1.x; As[lk + 1][lr + 64] = va1.y; As[lk + 2][lr + 64] = va1.z; As[lk + 3][lr + 64] = va1.w;
    Bs[lk + 0][lr] = vb0.x; Bs[lk + 1][lr] = vb0.y; Bs[lk + 2][lr] = vb0.z; Bs[lk + 3][lr] = vb0.w;
    Bs[lk + 0][lr + 64] = vb1.x; Bs[lk + 1][lr + 64] = vb1.y; Bs[lk + 2][lr + 64] = vb1.z; Bs[lk + 3][lr + 64] = vb1.w;
    __syncthreads();
#pragma unroll
    for (int k = 0; k < BK; ++k) {
      float a[8], b[8];
      *reinterpret_cast<float4*>(&a[0]) = *reinterpret_cast<const float4*>(&As[k][ty * 4]);
      *reinterpret_cast<float4*>(&a[4]) = *reinterpret_cast<const float4*>(&As[k][ty * 4 + 64]);
      *reinterpret_cast<float4*>(&b[0]) = *reinterpret_cast<const float4*>(&Bs[k][tx * 4]);
      *reinterpret_cast<float4*>(&b[4]) = *reinterpret_cast<const float4*>(&Bs[k][tx * 4 + 64]);
#pragma unroll
      for (int mm = 0; mm < 8; ++mm)
#pragma unroll
        for (int nn = 0; nn < 8; ++nn)
          acc[mm][nn] = fmaf(a[mm], b[nn], acc[mm][nn]);
    }
  }

  float sqj[8]; int tgtj[8];
#pragma unroll
  for (int nn = 0; nn < 8; ++nn) {
    int lc = tx * 4 + (nn & 3) + ((nn >> 2) << 6);
    sqj[nn] = sq[col0 + lc];
    tgtj[nn] = targets[col0 + lc];
  }
  float negsum = 0.f;
  unsigned int negc = 0u;
#pragma unroll
  for (int mm = 0; mm < 8; ++mm) {
    int lrow = ty * 4 + (mm & 3) + ((mm >> 2) << 6);
    int gi = row0 + lrow;
    float sqi = sq[gi];
    int tgti = targets[gi];
    float thr = min_pos[gi] + MARGIN_F;
    float rs = 0.f; int rc = 0;
#pragma unroll
    for (int nn = 0; nn < 8; ++nn) {
      float d2 = sqi + sqj[nn] - 2.f * acc[mm][nn];
      float dist = sqrtf(fmaxf(d2, 1e-12f));
      if (tgti != tgtj[nn]) {
        negsum += dist; negc++;
        if (dist < thr) { rc++; rs += dist; }
      }
    }
    if (rc) { atomicAdd(&red_cnt[lrow], rc); atomicAdd(&red_sel[lrow], rs); }
  }
#pragma unroll
  for (int off = 32; off > 0; off >>= 1) {
    negsum += __shfl_down(negsum, off, 64);
    negc += __shfl_down(negc, off, 64);
  }
  if ((tid & 63) == 0) { atomicAdd(&red_neg, negsum); atomicAdd(&red_negc, negc); }
  __syncthreads();
  if (tid < BM && red_cnt[tid] > 0) {
    atomicAdd(&sel_cnt[row0 + tid], red_cnt[tid]);
    atomicAdd(&sel_sum[row0 + tid], red_sel[tid]);
  }
  if (tid == 0) { atomicAdd(neg_total, red_neg); atomicAdd(neg_cnt, red_negc); }
}

// ---------------- finalize: 4 scalars ----------------
__global__ void nl_finalize(const float* __restrict__ min_pos, const float* __restrict__ pos_sum,
                            const int* __restrict__ pos_cnt, const float* __restrict__ sel_sum,
                            const int* __restrict__ sel_cnt, const float* __restrict__ neg_total,
                            const unsigned int* __restrict__ neg_cnt, float* __restrict__ out,
                            int n) {
  const int tid = threadIdx.x;
  float loss = 0.f, psum = 0.f;
  int nvalid = 0, pcnt = 0;
  for (int i = tid; i < n; i += 256) {
    int c = sel_cnt[i];
    if (c > 0) {
      float mean_neg = sel_sum[i] / (float)c;
      loss += min_pos[i] - mean_neg + MARGIN_F;
      nvalid++;
    }
    psum += pos_sum[i];
    pcnt += pos_cnt[i];
  }
  __shared__ float s_loss[256];
  __shared__ float s_psum[256];
  __shared__ int s_nv[256];
  __shared__ int s_pc[256];
  s_loss[tid] = loss; s_psum[tid] = psum; s_nv[tid] = nvalid; s_pc[tid] = pcnt;
  __syncthreads();
  for (int s = 128; s > 0; s >>= 1) {
    if (tid < s) {
      s_loss[tid] += s_loss[tid + s];
      s_psum[tid] += s_psum[tid + s];
      s_nv[tid] += s_nv[tid + s];
      s_pc[tid] += s_pc[tid + s];
    }
    __syncthreads();
  }
  if (tid == 0) {
    out[0] = s_loss[0] / (float)n;
    out[1] = 1.f - (float)s_nv[0] / (float)n;
    out[2] = s_psum[0] / (float)s_pc[0];
    out[3] = neg_total[0] / (float)neg_cnt[0];
  }
}

extern "C" void kernel_launch(void* const* d_in, const int* in_sizes, int n_in,
                              void* d_out, int out_size, void* d_ws, size_t ws_size,
                              hipStream_t stream) {
  const float* x = (const float*)d_in[0];
  const int* targets = (const int*)d_in[1];
  float* out = (float*)d_out;
  const int n = in_sizes[1];
  const int d = in_sizes[0] / n;

  // ws layout: stats block (8n+2 words), then (256B-aligned) f16 array
  float* sq = (float*)d_ws;
  float* min_pos = sq + n;
  float* pos_sum = min_pos + n;
  int* pos_cnt = (int*)(pos_sum + n);
  float* sel_sum = (float*)(pos_cnt + n);
  int* sel_cnt = (int*)(sel_sum + n);
  int* cls_start = (int*)(sel_cnt + n);
  int* members = cls_start + n;
  float* neg_total = (float*)(members + n);
  unsigned int* neg_cnt = (unsigned int*)(neg_total + 1);
  size_t stats_bytes = ((size_t)(8 * n + 2) * 4 + 255) & ~(size_t)255;
  ushort_t* xh = (ushort_t*)((char*)d_ws + stats_bytes);
  size_t need = stats_bytes + (size_t)n * d * sizeof(ushort_t);

  const bool mfma_ok = (ws_size >= need) && (n % 128) == 0 && (d % 32) == 0;
  const bool bucket_ok = (ws_size >= stats_bytes) && (n <= 8192) && (d % 16) == 0;

  nl_prep_kernel<<<dim3((n + 3) / 4), dim3(64, 4), 0, stream>>>(
      x, sq, mfma_ok ? xh : nullptr, neg_total, neg_cnt, n, d);
  if (bucket_ok) {
    nl_bucket_kernel<<<1, 1024, 0, stream>>>(targets, cls_start, members, n);
    nl_pos_bucket<<<(n * 64 + 255) / 256, 256, 0, stream>>>(
        x, targets, sq, cls_start, members, min_pos, pos_sum, pos_cnt, sel_sum, sel_cnt, n, d);
  } else {
    nl_pos_scan<<<(n * 64 + 255) / 256, 256, 0, stream>>>(
        x, targets, sq, min_pos, pos_sum, pos_cnt, sel_sum, sel_cnt, n, d);
  }

  if (mfma_ok) {
    int nbx = n / 128;
    int ntiles = nbx * (nbx + 1) / 2;
    nl_main_mfma<<<ntiles, 512, 0, stream>>>(xh, targets, sq, min_pos, sel_sum,
                                             sel_cnt, neg_total, neg_cnt, n, d);
  } else {
    nl_main_kernel<<<dim3(n / BN, n / BM), 256, 0, stream>>>(x, targets, sq, min_pos, sel_sum,
                                                             sel_cnt, neg_total, neg_cnt, n, d);
  }
  nl_finalize<<<1, 256, 0, stream>>>(min_pos, pos_sum, pos_cnt, sel_sum, sel_cnt,
                                     neg_total, neg_cnt, out, n);
}